// Round 9
// baseline (2040.477 us; speedup 1.0000x reference)
//
#include <hip/hip_runtime.h>
#include <cstdint>

#define BATCH 64
#define SEQ   512
#define DIM   512
#define MTOT  (BATCH*SEQ)   // 32768

// RNN decomposition: 16 column-slices (32 cols) x 16 batch-groups (4 rows)
// = 256 wgs. 4-phase row stagger; NO s_barrier in the scan loop.
#define CSL 16    // column slices (32 cols each)
#define GRP 16    // batch groups
#define RPG 4     // rows per group (= phases)
#define SLOT (GRP*RPG*DIM)   // 32768 pairs per parity slot

// ---------------------------------------------------------------------------
// Kernel 0: pack W_hh [c][j] -> Wpk[jb][c] (float4 over j%4); zero tag-pairs.
// hpair must be re-zeroed EVERY launch: stale tags from a previous run
// (graph replay) would false-match targets 1..511.
// ---------------------------------------------------------------------------
__global__ __launch_bounds__(128) void pack_w(const float* __restrict__ W,
                                              float4* __restrict__ Wpk,
                                              unsigned long long* __restrict__ hpair) {
    const int c  = blockIdx.x;
    const int jb = threadIdx.x;
    const float4 v = *(const float4*)&W[(size_t)c * DIM + 4 * jb];
    Wpk[(size_t)jb * DIM + c] = v;
    // 2 slots * GRP * RPG * DIM = 65536 pairs == gridDim.x * blockDim.x
    hpair[(size_t)blockIdx.x * 128 + threadIdx.x] = 0ull;
}

// ---------------------------------------------------------------------------
// Kernel 1: fused embedding gather + input projection (NT GEMM, fp32)
// ---------------------------------------------------------------------------
__global__ __launch_bounds__(256) void embed_proj(
    const int*   __restrict__ xidx,
    const float* __restrict__ emb,
    const float* __restrict__ W_ih,
    const float* __restrict__ b_ih,
    const float* __restrict__ b_hh,
    float*       __restrict__ xp) {
    __shared__ float As[64][68];  // As[k][m]
    __shared__ float Bs[64][68];  // Bs[k][n]

    const int m0  = blockIdx.x * 64;
    const int n0  = blockIdx.y * 64;
    const int tid = threadIdx.x;

    const int lr = tid >> 4;
    const int lc = (tid & 15) << 2;

    int rows[4];
#pragma unroll
    for (int i = 0; i < 4; i++) rows[i] = xidx[m0 + lr + 16 * i];

    const int tm = (tid & 15) << 2;
    const int tn = (tid >> 4) << 2;

    float acc[4][4];
#pragma unroll
    for (int i = 0; i < 4; i++)
#pragma unroll
        for (int j = 0; j < 4; j++) acc[i][j] = 0.0f;

    for (int k0 = 0; k0 < DIM; k0 += 64) {
#pragma unroll
        for (int i = 0; i < 4; i++) {
            const int rl = lr + 16 * i;
            const float4 a = *(const float4*)&emb[(size_t)rows[i] * DIM + k0 + lc];
            As[lc + 0][rl] = a.x; As[lc + 1][rl] = a.y;
            As[lc + 2][rl] = a.z; As[lc + 3][rl] = a.w;
            const float4 b = *(const float4*)&W_ih[(size_t)(n0 + rl) * DIM + k0 + lc];
            Bs[lc + 0][rl] = b.x; Bs[lc + 1][rl] = b.y;
            Bs[lc + 2][rl] = b.z; Bs[lc + 3][rl] = b.w;
        }
        __syncthreads();
#pragma unroll 8
        for (int kk = 0; kk < 64; kk++) {
            const float4 a = *(const float4*)&As[kk][tm];
            const float4 b = *(const float4*)&Bs[kk][tn];
            acc[0][0] = fmaf(a.x, b.x, acc[0][0]);
            acc[0][1] = fmaf(a.x, b.y, acc[0][1]);
            acc[0][2] = fmaf(a.x, b.z, acc[0][2]);
            acc[0][3] = fmaf(a.x, b.w, acc[0][3]);
            acc[1][0] = fmaf(a.y, b.x, acc[1][0]);
            acc[1][1] = fmaf(a.y, b.y, acc[1][1]);
            acc[1][2] = fmaf(a.y, b.z, acc[1][2]);
            acc[1][3] = fmaf(a.y, b.w, acc[1][3]);
            acc[2][0] = fmaf(a.z, b.x, acc[2][0]);
            acc[2][1] = fmaf(a.z, b.y, acc[2][1]);
            acc[2][2] = fmaf(a.z, b.z, acc[2][2]);
            acc[2][3] = fmaf(a.z, b.w, acc[2][3]);
            acc[3][0] = fmaf(a.w, b.x, acc[3][0]);
            acc[3][1] = fmaf(a.w, b.y, acc[3][1]);
            acc[3][2] = fmaf(a.w, b.z, acc[3][2]);
            acc[3][3] = fmaf(a.w, b.w, acc[3][3]);
        }
        __syncthreads();
    }

    const int n = n0 + tn;
    const float bias0 = b_ih[n + 0] + b_hh[n + 0];
    const float bias1 = b_ih[n + 1] + b_hh[n + 1];
    const float bias2 = b_ih[n + 2] + b_hh[n + 2];
    const float bias3 = b_ih[n + 3] + b_hh[n + 3];
#pragma unroll
    for (int i = 0; i < 4; i++) {
        float4 o;
        o.x = acc[i][0] + bias0;
        o.y = acc[i][1] + bias1;
        o.z = acc[i][2] + bias2;
        o.w = acc[i][3] + bias3;
        *(float4*)&xp[(size_t)(m0 + tm + i) * DIM + n] = o;
    }
}

// ---------------------------------------------------------------------------
// Kernel 2: RNN scan — 4-phase row stagger, NO s_barrier in the loop.
//  R8 post-mortem (race): a wave's poll is gated on the ELEMENT PUBLISHERS
//  (wgs of slices 2w,2w+1), not its own wg's reducer — so a fast wave can
//  lap into step t+1 phase p and (a) overwrite part[p][w] before its own
//  slow reducer read the step-t value, (b) push the monotone ctr to
//  8(t+1) with one wave's step-t contribution missing. Fixes:
//   - part[2][RPG][8][32]: step-parity double buffer. Overwrite of parity
//     q recurs at t+2, which happens-after THIS wg's reducer p published
//     t+1 (verified chain via all-16-wg tag gating), i.e. after its reads.
//   - done[p][w] step stamps (release) instead of a counter; reducer's 32
//     lanes each acquire-load done[p][lane&7] and spin on __all(>= t+1).
//     Lap-proof: a lapped wave's stamp t+2 >= t+1; its parity-q overwrite
//     is blocked by the part chain above.
//  Everything else unchanged from R8 (single-variable fix).
// ---------------------------------------------------------------------------
__global__ __launch_bounds__(512, 2)
void rnn_scan(const float4* __restrict__ Wpk, float* __restrict__ buf,
              unsigned long long* __restrict__ hpair) {
    __shared__ float    hlds[DIM];             // 2 KB, per-wave-private regions
    __shared__ float    part[2][RPG][8][32];   // 8 KB: [parity][phase][wave][col]
    __shared__ unsigned done_[RPG][8];         // per-(phase,wave) step stamps

    const int tid   = threadIdx.x;
    const int slice = blockIdx.x / GRP;   // 0..15
    const int grp   = blockIdx.x % GRP;   // 0..15
    const int c     = tid & 31;           // col within slice
    const int z     = tid >> 5;           // k-chunk (32 wide), 0..15
    const int wv    = tid >> 6;           // wave id 0..7
    const int lane  = tid & 63;
    const int b0    = grp * RPG;
    const int col0  = slice * 32;

    if (tid < RPG * 8) ((unsigned*)done_)[tid] = 0u;
    hlds[tid] = 0.0f;
    __syncthreads();   // one-time init barrier (only barrier in the kernel)

    // W slice: lane holds W[col0+c][32z .. 32z+32) as 8 float4.
    // Volatile inline-asm loads: non-rematerializable by construction.
    float4 wr[8];
    {
        const float4* wp = Wpk + (size_t)(8 * z) * DIM + col0 + c;
#pragma unroll
        for (int i = 0; i < 8; i++)
            asm volatile("global_load_dwordx4 %0, %1, off"
                         : "=v"(wr[i]) : "v"(wp + (size_t)i * DIM));
        asm volatile("s_waitcnt vmcnt(0)" ::: "memory");
        __builtin_amdgcn_sched_barrier(0);   // nothing crosses the wait
    }

    // Poll base: lane tid polls h[row][tid] of its group.
    unsigned long long* const pbase = hpair + (size_t)grp * (RPG * DIM);

    // Wave r (r < RPG), lanes 0..31: reducer/publisher for row r.
    size_t bufr = 0;
    unsigned long long* pubp = nullptr;
    float xq = 0.0f;
    if (wv < RPG && lane < 32) {
        bufr = (size_t)(b0 + wv) * SEQ * DIM + col0 + c;
        xq   = buf[bufr];                                  // xp[row][0][col]
        pubp = hpair + ((size_t)grp * RPG + wv) * DIM + col0 + c;
    }

    unsigned long long pend[4] = {0ull, 0ull, 0ull, 0ull};

    for (int t = 0; t < SEQ; t++) {
#pragma unroll
        for (int p = 0; p < RPG; p++) {
            // ---- poll row p, tag t (skip at t=0: h(0)=0 already in LDS) ----
            if (t > 0) {
                const unsigned tgt = (unsigned)t;
                unsigned long long v = pend[p];        // static idx (unrolled)
                if ((unsigned)(v >> 32) != tgt) {
                    const unsigned long long* sp =
                        pbase + (size_t)(t & 1) * SLOT + p * DIM + tid;
                    int spins = 0;
                    do {
                        if (++spins > 16) __builtin_amdgcn_s_sleep(1);
                        v = __hip_atomic_load(sp, __ATOMIC_RELAXED,
                                              __HIP_MEMORY_SCOPE_AGENT);
                    } while ((unsigned)(v >> 32) != tgt);
                }
                hlds[tid] = __uint_as_float((unsigned)v);
                asm volatile("" ::: "memory");   // own-wave write before read
            }

            // ---- dot: partial over k-chunk [32z,32z+32) for col c ----
            {
                const float4* hz = (const float4*)hlds + 8 * z;
                float4 a = make_float4(0.f, 0.f, 0.f, 0.f);
#pragma unroll
                for (int i = 0; i < 8; i++) {
                    const float4 w = wr[i];
                    const float4 h = hz[i];
                    a.x = fmaf(w.x, h.x, a.x);
                    a.y = fmaf(w.y, h.y, a.y);
                    a.z = fmaf(w.z, h.z, a.z);
                    a.w = fmaf(w.w, h.w, a.w);
                }
                float s = (a.x + a.y) + (a.z + a.w);
                s += __shfl_xor(s, 32);          // combine the two half-waves
                if (lane < 32) part[t & 1][p][wv][c] = s;
                if (lane == 0)
                    __hip_atomic_store(&done_[p][wv], (unsigned)(t + 1),
                                       __ATOMIC_RELEASE,
                                       __HIP_MEMORY_SCOPE_WORKGROUP);
            }

            // ---- prefetch pend for row (p+2)&3 (2 phases post-publish) ----
            {
                const int r2 = (p + 2) & 3;
                const int tl = t + ((p + 2) >> 2);
                pend[r2] = __hip_atomic_load(
                    pbase + (size_t)(tl & 1) * SLOT + r2 * DIM + tid,
                    __ATOMIC_RELAXED, __HIP_MEMORY_SCOPE_AGENT);
            }

            // ---- reducer: stamp sync (no s_barrier, no vmcnt drain) ----
            if (wv == p && lane < 32) {
                const unsigned want = (unsigned)(t + 1);
                int sp_ = 0;
                while (true) {
                    const unsigned st = __hip_atomic_load(
                        &done_[p][lane & 7], __ATOMIC_ACQUIRE,
                        __HIP_MEMORY_SCOPE_WORKGROUP);
                    if (__all(st >= want)) break;
                    if ((++sp_ & 3) == 0) __builtin_amdgcn_s_sleep(1);
                }
                const int q = t & 1;
                float s = part[q][p][0][c];
#pragma unroll
                for (int k = 1; k < 8; k++) s += part[q][p][k][c];
                const float hn = tanhf(xq + s);
                if (t + 1 < SEQ) {
                    // fused data+tag: one 8B atomic, publish FIRST
                    const unsigned long long pv =
                        ((unsigned long long)(unsigned)(t + 1) << 32) |
                        (unsigned long long)__float_as_uint(hn);
                    __hip_atomic_store(pubp + (size_t)((t + 1) & 1) * SLOT, pv,
                                       __ATOMIC_RELAXED, __HIP_MEMORY_SCOPE_AGENT);
                }
                buf[bufr + (size_t)t * DIM] = hn;
                const int tn2 = (t + 1 < SEQ) ? (t + 1) : t;
                xq = buf[bufr + (size_t)tn2 * DIM];   // in flight a full step
            }
        }
    }
}

// ---------------------------------------------------------------------------
// Kernel 3: softmax over H (per b,t) + transpose [B][T][H] -> out [B][H][T]
// ---------------------------------------------------------------------------
__global__ __launch_bounds__(256) void softmax_T(const float* __restrict__ hid,
                                                 float* __restrict__ out) {
    __shared__ float rowmax[64];
    __shared__ float rowinv[64];
    __shared__ float tile[64][65];

    const int b   = blockIdx.x;
    const int t0  = blockIdx.y * 64;
    const int tid = threadIdx.x;
    const float* base = hid + ((size_t)b * SEQ + t0) * DIM;

    const int r = tid >> 2;
    const int p = tid & 3;

    float m = -1e30f;
#pragma unroll 4
    for (int k = 0; k < 32; k++) {
        const float4 v = *(const float4*)&base[r * DIM + ((k * 4 + p) << 2)];
        m = fmaxf(m, fmaxf(fmaxf(v.x, v.y), fmaxf(v.z, v.w)));
    }
    m = fmaxf(m, __shfl_xor(m, 1));
    m = fmaxf(m, __shfl_xor(m, 2));

    float s = 0.0f;
#pragma unroll 4
    for (int k = 0; k < 32; k++) {
        const float4 v = *(const float4*)&base[r * DIM + ((k * 4 + p) << 2)];
        s += expf(v.x - m) + expf(v.y - m) + expf(v.z - m) + expf(v.w - m);
    }
    s += __shfl_xor(s, 1);
    s += __shfl_xor(s, 2);
    if (p == 0) {
        rowmax[r] = m;
        rowinv[r] = 1.0f / s;
    }
    __syncthreads();

    for (int hc = 0; hc < 8; hc++) {
#pragma unroll
        for (int i = 0; i < 16; i++) {
            const int lin = tid + 256 * i;
            const int rrr = lin >> 6;
            const int ccc = lin & 63;
            const float v = base[rrr * DIM + hc * 64 + ccc];
            tile[ccc][rrr] = expf(v - rowmax[rrr]) * rowinv[rrr];
        }
        __syncthreads();
#pragma unroll
        for (int i = 0; i < 16; i++) {
            const int lin = tid + 256 * i;
            const int hh  = lin >> 6;
            const int tt  = lin & 63;
            out[((size_t)b * DIM + hc * 64 + hh) * SEQ + t0 + tt] = tile[hh][tt];
        }
        __syncthreads();
    }
}

// ---------------------------------------------------------------------------
extern "C" void kernel_launch(void* const* d_in, const int* in_sizes, int n_in,
                              void* d_out, int out_size, void* d_ws, size_t ws_size,
                              hipStream_t stream) {
    const int*   x    = (const int*)  d_in[0];
    const float* emb  = (const float*)d_in[1];
    const float* W_ih = (const float*)d_in[2];
    const float* W_hh = (const float*)d_in[3];
    const float* b_ih = (const float*)d_in[4];
    const float* b_hh = (const float*)d_in[5];
    float* out = (float*)d_out;

    // 64 MB scratch: xp (then hid, in place) as [B][T][H]
    float* buf = (float*)d_ws;
    // staging inside d_out (16.7M floats); all consumed before softmax_T
    // overwrites d_out (stream-ordered):
    float4* Wpk = (float4*)out;                                   // 1M floats
    unsigned long long* hpair =
        (unsigned long long*)(out + (4 << 20));                   // 512 KB tagged pairs

    pack_w<<<dim3(DIM), 128, 0, stream>>>(W_hh, Wpk, hpair);
    embed_proj<<<dim3(MTOT / 64, DIM / 64), 256, 0, stream>>>(x, emb, W_ih, b_ih, b_hh, buf);
    rnn_scan<<<CSL * GRP, 512, 0, stream>>>(Wpk, buf, hpair);
    softmax_T<<<dim3(BATCH, SEQ / 64), 256, 0, stream>>>(buf, out);
}